// Round 8
// baseline (126.590 us; speedup 1.0000x reference)
//
#include <hip/hip_runtime.h>

#define N_PTS  20000
#define NG     128                  // grid NG x NG over [-6,6]^2
#define NC     (NG * NG)            // 16384 cells per cloud
#define GMIN   (-6.0f)
#define GINV   (NG / 12.0f)
#define MARGIN 5e-4f                // >> 2e-5 worst-case |P_np - d_true^2|
#define SSTRIDE (N_PTS / 64)        // 312; 63*312 = 19656 < 20000
#define QB79   79                   // fallback

// ---- numpy-exact helpers (proven rounds 2/5/9/10/11/14) ----
__device__ __forceinline__ float np_self_dot(float x, float y, float z) {
    return __fadd_rn(__fadd_rn(__fmul_rn(x, x), __fmul_rn(y, y)),
                     __fmul_rn(z, z));
}
__device__ __forceinline__ unsigned ordmap(float f) {
    unsigned b = __float_as_uint(f);
    return (b & 0x80000000u) ? ~b : (b | 0x80000000u);
}
__device__ __forceinline__ float invord(unsigned h) {
    return __uint_as_float((h & 0x80000000u) ? (h ^ 0x80000000u) : ~h);
}
__device__ __forceinline__ int cellC(float v) {
    int c = (int)((v - GMIN) * GINV);
    return c < 0 ? 0 : (c > NG - 1 ? NG - 1 : c);
}
__device__ __forceinline__ unsigned long long wave_min_u64(unsigned long long k) {
    #pragma unroll
    for (int m = 1; m < 64; m <<= 1) {
        unsigned long long o = __shfl_xor(k, m, 64);
        k = (o < k) ? o : k;
    }
    return k;
}

// ---- build A1 (r16/r18, PROVEN): wide parallel histogram, global atomics ----
__global__ __launch_bounds__(256) void k_hist(
    const float* __restrict__ preds, const float* __restrict__ gts,
    int* __restrict__ cursor)
{
    int t = blockIdx.x * 256 + threadIdx.x;
    if (t >= 2 * N_PTS) return;
    int cl = t / N_PTS, i = t - cl * N_PTS;
    const float* src = cl ? gts : preds;
    int cell = cellC(src[i*3+0]) * NG + cellC(src[i*3+1]);
    atomicAdd(&cursor[cl * NC + cell], 1);
}

// ---- build A2 (r22): scan via shfl wave-scans, 2 barriers (was 20).
// Same contract as r16/r18 k_scan: reads counts from cursor, writes
// exclusive starts to bstart+cursor, sentinel bstart[NC]=N_PTS.
__global__ __launch_bounds__(1024) void k_scan(
    int* __restrict__ cursor, int* __restrict__ bstart)
{
    __shared__ int wsum[16];
    __shared__ int wpre[16];
    int cl = blockIdx.x, t = threadIdx.x;
    int wave = t >> 6, lane = t & 63;

    int base = cl * NC + t * 16;                    // 64B-aligned (ws layout)
    const int4* c4 = (const int4*)(cursor + base);
    int4 a = c4[0], b = c4[1], c = c4[2], d = c4[3];
    int v[16] = { a.x, a.y, a.z, a.w, b.x, b.y, b.z, b.w,
                  c.x, c.y, c.z, c.w, d.x, d.y, d.z, d.w };
    int s = 0;
    #pragma unroll
    for (int i = 0; i < 16; ++i) s += v[i];

    int ps = s;                                     // inclusive 64-lane scan
    #pragma unroll
    for (int m = 1; m < 64; m <<= 1) {
        int o = __shfl_up(ps, m, 64);
        if (lane >= m) ps += o;
    }
    if (lane == 63) wsum[wave] = ps;
    __syncthreads();
    if (t < 16) {
        int x = wsum[t];
        int px = x;                                 // inclusive 16-scan
        #pragma unroll
        for (int m = 1; m < 16; m <<= 1) {
            int o = __shfl_up(px, m, 16);
            if ((t & 15) >= m) px += o;
        }
        wpre[t] = px - x;                           // exclusive wave prefix
    }
    __syncthreads();

    int run = wpre[wave] + (ps - s);                // exclusive thread prefix
    #pragma unroll
    for (int i = 0; i < 16; ++i) {
        bstart[cl * (NC + 1) + t * 16 + i] = run;
        cursor[base + i] = run;
        run += v[i];
    }
    if (t == 1023) bstart[cl * (NC + 1) + NC] = run;   // == N_PTS
}

// ---- build B (r15/r18, PROVEN): wide scatter into cell-sorted order ----
__global__ __launch_bounds__(256) void k_scatter(
    const float* __restrict__ preds, const float* __restrict__ gts,
    int* __restrict__ cursor, float4* __restrict__ sorted)
{
    int t = blockIdx.x * 256 + threadIdx.x;
    if (t >= 2 * N_PTS) return;
    int cl = t / N_PTS, i = t - cl * N_PTS;
    const float* src = cl ? gts : preds;
    float x = src[i*3+0], y = src[i*3+1], z = src[i*3+2];
    int cell = cellC(x) * NG + cellC(y);
    int pos = atomicAdd(&cursor[cl * NC + cell], 1);
    sorted[(size_t)cl * N_PTS + pos] = make_float4(x, y, z, __int_as_float(i));
}

// ---- main (r22): contiguous-SPAN scanning. Cells are row-major sorted,
// so box [xL..xR]x[yL..yR] lies inside ONE contiguous index interval
// [cs[xL*NG+yL], cs[xR*NG+yR+1]). Scanning the whole interval evaluates a
// SUPERSET of the box — every extra point is a genuine candidate, so
// min/argmin are unchanged (all min-P points lie inside the W-box, which
// is inside the scanned set; key/tie-break identical to r9-r21). This
// removes all per-row machinery: per phase 2 scalar bound loads -> one
// streamed loop, 4 loads in flight. Dependent-chain per query ~5-7 L2
// trips (was ~8-25 rowwise). Extra points are L2-resident reads (r21
// FETCH 4.2MB == 8 XCDs x 640KB: both clouds L2-cached) at ~10% VALU —
// surplus throughput traded for scarce latency.
// W-certificate unchanged: W^2 = d_seed + MARGIN; every point with
// P <= W^2 is in the W-box span; flanks [lo2,slo) and [shi,hi2) complete
// its coverage; over-scan harmless; rescans idempotent; samp EVAL
// guarantees a valid upper bound (no empty-seed path).
__global__ __launch_bounds__(64) void k_main(
    const float4* __restrict__ sorted, const int* __restrict__ bstart,
    float* __restrict__ out)
{
    int wid  = blockIdx.x;                                 // 0..39999
    int lane = threadIdx.x;                                // 0..63
    int dir  = wid / N_PTS;
    int qpos = wid - dir * N_PTS;
    int rcl  = 1 - dir;

    const float4* rs = sorted + (size_t)rcl * N_PTS;
    const int*    cs = bstart + rcl * (NC + 1);

    float4 samp = rs[lane * SSTRIDE];                  // independent, early
    float4 qv   = sorted[(size_t)dir * N_PTS + qpos];  // wave-broadcast
    int    origq = __float_as_int(qv.w);
    float qx = qv.x, qy = qv.y, qz = qv.z;
    float sq = np_self_dot(qx, qy, qz);

    unsigned long long key = ~0ULL;

#define EVAL(r)                                                            \
    {   float sr = np_self_dot((r).x, (r).y, (r).z);                       \
        float zz = __fadd_rn(__fadd_rn(__fmul_rn(qx, (r).x),               \
                                       __fmul_rn(qy, (r).y)),              \
                             __fmul_rn(qz, (r).z));                        \
        float P  = __fsub_rn(__fadd_rn(sq, sr), __fadd_rn(zz, zz));        \
        unsigned long long kk =                                            \
            ((unsigned long long)ordmap(P) << 32) | __float_as_uint((r).w);\
        key = (kk < key) ? kk : key; }

// Stream candidates [LO,HI): lane-strided, up to 4 loads in flight.
// Coverage per lane: indices LO+lane+64k < HI, processed 4/2/1 at a time.
#define STREAM(LO, HI)                                                     \
    {   int p = (LO) + lane;                                               \
        for (; p + 192 < (HI); p += 256) {                                 \
            float4 r0 = rs[p],       r1 = rs[p + 64];                      \
            float4 r2 = rs[p + 128], r3 = rs[p + 192];                     \
            EVAL(r0) EVAL(r1) EVAL(r2) EVAL(r3)                            \
        }                                                                  \
        for (; p + 64 < (HI); p += 128) {                                  \
            float4 r0 = rs[p], r1 = rs[p + 64];                            \
            EVAL(r0) EVAL(r1)                                              \
        }                                                                  \
        if (p < (HI)) { float4 r0 = rs[p]; EVAL(r0) }                      \
    }

    // phase 1: seed = contiguous span of the 3x3 cell box (superset)
    int cx = cellC(qx), cy = cellC(qy);
    int sxL = cx > 0 ? cx - 1 : 0, sxR = cx < NG-1 ? cx + 1 : NG-1;
    int syL = cy > 0 ? cy - 1 : 0, syR = cy < NG-1 ? cy + 1 : NG-1;
    int slo = cs[sxL * NG + syL];                      // scalar loads
    int shi = cs[sxR * NG + syR + 1];
    STREAM(slo, shi)
    EVAL(samp)                        // guaranteed-valid upper bound

    // phase 2: certified W-span; stream only the flanks not yet scanned
    key = wave_min_u64(key);
    float W = sqrtf(invord((unsigned)(key >> 32)) + MARGIN);
    int txL = cellC(qx - W), txR = cellC(qx + W);
    int tyL = cellC(qy - W), tyR = cellC(qy + W);
    int lo2 = cs[txL * NG + tyL];
    int hi2 = cs[txR * NG + tyR + 1];
    if (lo2 < slo) STREAM(lo2, slo)
    if (hi2 > shi) STREAM(shi, hi2)
    key = wave_min_u64(key);
#undef STREAM
#undef EVAL

    if (lane == 0) {
        out[dir * N_PTS + origq]       = invord((unsigned)(key >> 32));
        out[(2 + dir) * N_PTS + origq] = (float)(unsigned)(key & 0xFFFFFFFFu);
    }
}

// ---- fallback (tiny workspace): brute-force direct kernel (proven r2) ----
__device__ __forceinline__ float np_pair(float sq, float sr,
                                         float qx, float qy, float qz,
                                         float rx, float ry, float rz) {
    float zz = __fadd_rn(__fadd_rn(__fmul_rn(qx, rx), __fmul_rn(qy, ry)),
                         __fmul_rn(qz, rz));
    return __fsub_rn(__fadd_rn(sq, sr), __fadd_rn(zz, zz));
}

__global__ __launch_bounds__(256) void chamfer_direct_kernel(
    const float* __restrict__ preds, const float* __restrict__ gts,
    float* __restrict__ out)
{
    __shared__ float4 spts[256];
    int bid = blockIdx.x;
    int dir = bid / QB79;
    int qb  = bid - dir * QB79;
    int q   = qb * 256 + threadIdx.x;

    const float* qpts = (dir == 0) ? preds : gts;
    const float* rpts = (dir == 0) ? gts   : preds;

    int qc = (q < N_PTS) ? q : (N_PTS - 1);
    float qx = qpts[qc*3+0], qy = qpts[qc*3+1], qz = qpts[qc*3+2];
    float sq = np_self_dot(qx, qy, qz);
    float best = 3.4e38f;
    int   bidx = 0;

    for (int t = 0; t < N_PTS; t += 256) {
        int cnt = min(256, N_PTS - t);
        __syncthreads();
        if ((int)threadIdx.x < cnt) {
            int j = t + threadIdx.x;
            float rx = rpts[j*3+0], ry = rpts[j*3+1], rz = rpts[j*3+2];
            spts[threadIdx.x] = make_float4(rx, ry, rz, np_self_dot(rx, ry, rz));
        }
        __syncthreads();
        for (int k = 0; k < cnt; ++k) {
            float4 r = spts[k];
            float d = np_pair(sq, r.w, qx, qy, qz, r.x, r.y, r.z);
            if (d < best) { best = d; bidx = t + k; }
        }
    }
    if (q < N_PTS) {
        out[dir * N_PTS + q]       = best;
        out[(2 + dir) * N_PTS + q] = (float)bidx;
    }
}

extern "C" void kernel_launch(void* const* d_in, const int* in_sizes, int n_in,
                              void* d_out, int out_size, void* d_ws, size_t ws_size,
                              hipStream_t stream) {
    const float* preds = (const float*)d_in[0];  // [20000, 3]
    const float* gts   = (const float*)d_in[1];  // [1, 20000, 3]
    float* out = (float*)d_out;

    char* w = (char*)d_ws;
    size_t sorted_b = (size_t)2 * N_PTS * sizeof(float4);   // 640000
    size_t bstart_b = (size_t)2 * (NC + 1) * sizeof(int);   // 131080
    size_t cursor_b = (size_t)2 * NC * sizeof(int);         // 131072
    size_t need = sorted_b + bstart_b + cursor_b;

    if (ws_size >= need) {
        float4* sorted = (float4*)w;
        int* bstart = (int*)(w + sorted_b);
        int* cursor = (int*)(w + sorted_b + bstart_b);

        hipMemsetAsync(cursor, 0, cursor_b, stream);
        k_hist<<<(2 * N_PTS + 255) / 256, 256, 0, stream>>>(preds, gts, cursor);
        k_scan<<<2, 1024, 0, stream>>>(cursor, bstart);
        k_scatter<<<(2 * N_PTS + 255) / 256, 256, 0, stream>>>(
            preds, gts, cursor, sorted);
        k_main<<<2 * N_PTS, 64, 0, stream>>>(sorted, bstart, out);
    } else {
        chamfer_direct_kernel<<<2 * QB79, 256, 0, stream>>>(preds, gts, out);
    }
}

// Round 9
// 122.402 us; speedup vs baseline: 1.0342x; 1.0342x over previous
//
#include <hip/hip_runtime.h>

#define N_PTS  20000
#define NG     128                  // grid NG x NG over [-6,6]^2
#define NC     (NG * NG)            // 16384 cells per cloud
#define GMIN   (-6.0f)
#define GINV   (NG / 12.0f)
#define MARGIN 5e-4f                // >> 2e-5 worst-case |P_np - d_true^2|
#define SSTRIDE (N_PTS / 64)        // 312; 63*312 = 19656 < 20000
#define QB79   79                   // fallback

// ---- numpy-exact helpers (proven rounds 2/5/9/10/11/14) ----
__device__ __forceinline__ float np_self_dot(float x, float y, float z) {
    return __fadd_rn(__fadd_rn(__fmul_rn(x, x), __fmul_rn(y, y)),
                     __fmul_rn(z, z));
}
__device__ __forceinline__ unsigned ordmap(float f) {
    unsigned b = __float_as_uint(f);
    return (b & 0x80000000u) ? ~b : (b | 0x80000000u);
}
__device__ __forceinline__ float invord(unsigned h) {
    return __uint_as_float((h & 0x80000000u) ? (h ^ 0x80000000u) : ~h);
}
__device__ __forceinline__ int cellC(float v) {
    int c = (int)((v - GMIN) * GINV);
    return c < 0 ? 0 : (c > NG - 1 ? NG - 1 : c);
}
__device__ __forceinline__ unsigned long long wave_min_u64(unsigned long long k) {
    #pragma unroll
    for (int m = 1; m < 64; m <<= 1) {
        unsigned long long o = __shfl_xor(k, m, 64);
        k = (o < k) ? o : k;
    }
    return k;
}

// Candidate evaluation (bit-identical numerics, key=(ordmap(P)<<32|idx)).
// Uses names qx,qy,qz,sq,key from the enclosing scope.
#define EVAL(r)                                                            \
    {   float sr = np_self_dot((r).x, (r).y, (r).z);                       \
        float zz = __fadd_rn(__fadd_rn(__fmul_rn(qx, (r).x),               \
                                       __fmul_rn(qy, (r).y)),              \
                             __fmul_rn(qz, (r).z));                        \
        float P  = __fsub_rn(__fadd_rn(sq, sr), __fadd_rn(zz, zz));        \
        unsigned long long kk =                                            \
            ((unsigned long long)ordmap(P) << 32) | __float_as_uint((r).w);\
        key = (kk < key) ? kk : key; }

// ---- 3-row flat stream (r23): lanes walk the concatenated candidate
// space of up to 3 y-clipped row intervals [lo_i, lo_i+c_i). Row lookup is
// a 2-comparison ternary map (no binary search — the r19/r20 flattened
// scan is banned). Software-pipelined 2-deep. Covers each interval exactly
// once; zero-count rows skipped; all candidates genuine points => min
// semantics exact.
__device__ __forceinline__ void stream3(
    const float4* __restrict__ rs, int lane,
    int lo0, int c0, int lo1, int c1, int lo2, int c2,
    float qx, float qy, float qz, float sq, unsigned long long& key)
{
    int s01 = c0 + c1, tot = s01 + c2;
    int t = lane;
    if (t < tot) {
        int p = t < c0 ? lo0 + t : t < s01 ? lo1 + (t - c0) : lo2 + (t - s01);
        float4 rc = rs[p];
        for (t += 64; t < tot; t += 64) {
            int pn = t < c0 ? lo0 + t : t < s01 ? lo1 + (t - c0)
                                                : lo2 + (t - s01);
            float4 rn = rs[pn];                       // next load in flight
            EVAL(rc)
            rc = rn;
        }
        EVAL(rc)
    }
}

// ---- build A1 (r16/r18, PROVEN): wide parallel histogram, global atomics ----
__global__ __launch_bounds__(256) void k_hist(
    const float* __restrict__ preds, const float* __restrict__ gts,
    int* __restrict__ cursor)
{
    int t = blockIdx.x * 256 + threadIdx.x;
    if (t >= 2 * N_PTS) return;
    int cl = t / N_PTS, i = t - cl * N_PTS;
    const float* src = cl ? gts : preds;
    int cell = cellC(src[i*3+0]) * NG + cellC(src[i*3+1]);
    atomicAdd(&cursor[cl * NC + cell], 1);
}

// ---- build A2 (r22, PROVEN): scan via shfl wave-scans, 2 barriers ----
__global__ __launch_bounds__(1024) void k_scan(
    int* __restrict__ cursor, int* __restrict__ bstart)
{
    __shared__ int wsum[16];
    __shared__ int wpre[16];
    int cl = blockIdx.x, t = threadIdx.x;
    int wave = t >> 6, lane = t & 63;

    int base = cl * NC + t * 16;                    // 64B-aligned (ws layout)
    const int4* c4 = (const int4*)(cursor + base);
    int4 a = c4[0], b = c4[1], c = c4[2], d = c4[3];
    int v[16] = { a.x, a.y, a.z, a.w, b.x, b.y, b.z, b.w,
                  c.x, c.y, c.z, c.w, d.x, d.y, d.z, d.w };
    int s = 0;
    #pragma unroll
    for (int i = 0; i < 16; ++i) s += v[i];

    int ps = s;                                     // inclusive 64-lane scan
    #pragma unroll
    for (int m = 1; m < 64; m <<= 1) {
        int o = __shfl_up(ps, m, 64);
        if (lane >= m) ps += o;
    }
    if (lane == 63) wsum[wave] = ps;
    __syncthreads();
    if (t < 16) {
        int x = wsum[t];
        int px = x;                                 // inclusive 16-scan
        #pragma unroll
        for (int m = 1; m < 16; m <<= 1) {
            int o = __shfl_up(px, m, 16);
            if ((t & 15) >= m) px += o;
        }
        wpre[t] = px - x;                           // exclusive wave prefix
    }
    __syncthreads();

    int run = wpre[wave] + (ps - s);                // exclusive thread prefix
    #pragma unroll
    for (int i = 0; i < 16; ++i) {
        bstart[cl * (NC + 1) + t * 16 + i] = run;
        cursor[base + i] = run;
        run += v[i];
    }
    if (t == 1023) bstart[cl * (NC + 1) + NC] = run;   // == N_PTS
}

// ---- build B (r15/r18, PROVEN): wide scatter into cell-sorted order ----
__global__ __launch_bounds__(256) void k_scatter(
    const float* __restrict__ preds, const float* __restrict__ gts,
    int* __restrict__ cursor, float4* __restrict__ sorted)
{
    int t = blockIdx.x * 256 + threadIdx.x;
    if (t >= 2 * N_PTS) return;
    int cl = t / N_PTS, i = t - cl * N_PTS;
    const float* src = cl ? gts : preds;
    float x = src[i*3+0], y = src[i*3+1], z = src[i*3+2];
    int cell = cellC(x) * NG + cellC(y);
    int pos = atomicAdd(&cursor[cl * NC + cell], 1);
    sorted[(size_t)cl * N_PTS + pos] = make_float4(x, y, z, __int_as_float(i));
}

// ---- main (r23): y-clipped rows + parallel flat loading.
// r22 post-mortem: span scan fixed latency (VALU 68%, occ 52%) but scans
// the FULL-y extent of each grid-row (~750 pts/row center) — ~10x wasted
// EVALs. r23 keeps the parallel-load structure but clips y:
//  seed: ONE lane-scattered bounds load (lanes 0..2 row starts @syL,
//        lanes 32..34 row ends @syR+1) -> 3-row flat stream (~150-250
//        candidates, 2-comparison row map, 2-deep pipelined).
//  phase2 (only if W-box escapes seed): ONE bounds load per <=32 rows,
//        rows processed in triples straight from registers (shfl) — no
//        further bound loads; covers exactly the W-box cells.
// W-certificate unchanged (r18): W^2 = d_seed + MARGIN; any unscanned
// point has P > W^2 > d_final + numerics. Rescans idempotent. samp EVAL
// guarantees a valid bound (no empty-seed path). Numerics bit-identical
// to r9-r22: numpy-exact P; key=(ordmap(P)<<32|idx); wave-min == numpy
// first-occurrence argmin.
__global__ __launch_bounds__(64) void k_main(
    const float4* __restrict__ sorted, const int* __restrict__ bstart,
    float* __restrict__ out)
{
    int wid  = blockIdx.x;                                 // 0..39999
    int lane = threadIdx.x;                                // 0..63
    int dir  = wid / N_PTS;
    int qpos = wid - dir * N_PTS;
    int rcl  = 1 - dir;

    const float4* rs = sorted + (size_t)rcl * N_PTS;
    const int*    cs = bstart + rcl * (NC + 1);

    float4 samp = rs[lane * SSTRIDE];                  // independent, early
    float4 qv   = sorted[(size_t)dir * N_PTS + qpos];  // wave-broadcast
    int    origq = __float_as_int(qv.w);
    float qx = qv.x, qy = qv.y, qz = qv.z;
    float sq = np_self_dot(qx, qy, qz);

    unsigned long long key = ~0ULL;
    int l31 = lane & 31;

    // phase 1: seed = 3x3 cell box, y-clipped rows, one bounds load
    int cx = cellC(qx), cy = cellC(qy);
    int sxL = cx > 0 ? cx - 1 : 0, sxR = cx < NG-1 ? cx + 1 : NG-1;
    int syL = cy > 0 ? cy - 1 : 0, syR = cy < NG-1 ? cy + 1 : NG-1;
    int nrs  = sxR - sxL + 1;                          // 2 or 3
    int xrS  = sxL + (l31 < nrs ? l31 : nrs - 1);
    int colS = (lane < 32) ? syL : (syR + 1);          // end = next col start
    int bndS = cs[xrS * NG + colS];                    // ONE scattered load
    int lo0 = __shfl(bndS, 0, 64), hi0 = __shfl(bndS, 32, 64);
    int lo1 = __shfl(bndS, 1, 64), hi1 = __shfl(bndS, 33, 64);
    int lo2 = __shfl(bndS, 2, 64), hi2 = __shfl(bndS, 34, 64);
    int c0 = hi0 - lo0;
    int c1 = nrs > 1 ? hi1 - lo1 : 0;
    int c2 = nrs > 2 ? hi2 - lo2 : 0;
    stream3(rs, lane, lo0, c0, lo1, c1, lo2, c2, qx, qy, qz, sq, key);
    EVAL(samp)                        // guaranteed-valid upper bound

    // phase 2: certified W-box scan (exact cells, rescans idempotent)
    key = wave_min_u64(key);
    float W = sqrtf(invord((unsigned)(key >> 32)) + MARGIN);
    int txL = cellC(qx - W), txR = cellC(qx + W);
    int tyL = cellC(qy - W), tyR = cellC(qy + W);
    if (!(txL >= sxL && txR <= sxR && tyL >= syL && tyR <= syR)) {
        int R = txR - txL + 1;
        for (int g = 0; g < R; g += 32) {
            int rows = R - g; if (rows > 32) rows = 32;
            int xr2  = txL + g + (l31 < rows ? l31 : rows - 1);
            int col2 = (lane < 32) ? tyL : (tyR + 1);
            int b2 = cs[xr2 * NG + col2];              // ONE load / 32 rows
            for (int r0 = 0; r0 < rows; r0 += 3) {     // triples from regs
                int i1 = r0 + 1 < rows ? r0 + 1 : rows - 1;
                int i2 = r0 + 2 < rows ? r0 + 2 : rows - 1;
                int L0 = __shfl(b2, r0, 64), H0 = __shfl(b2, 32 + r0, 64);
                int L1 = __shfl(b2, i1, 64), H1 = __shfl(b2, 32 + i1, 64);
                int L2 = __shfl(b2, i2, 64), H2 = __shfl(b2, 32 + i2, 64);
                int d0 = H0 - L0;
                int d1 = (r0 + 1 < rows) ? H1 - L1 : 0;
                int d2 = (r0 + 2 < rows) ? H2 - L2 : 0;
                stream3(rs, lane, L0, d0, L1, d1, L2, d2,
                        qx, qy, qz, sq, key);
            }
        }
        key = wave_min_u64(key);
    }

    if (lane == 0) {
        out[dir * N_PTS + origq]       = invord((unsigned)(key >> 32));
        out[(2 + dir) * N_PTS + origq] = (float)(unsigned)(key & 0xFFFFFFFFu);
    }
}

// ---- fallback (tiny workspace): brute-force direct kernel (proven r2) ----
__device__ __forceinline__ float np_pair(float sq, float sr,
                                         float qx, float qy, float qz,
                                         float rx, float ry, float rz) {
    float zz = __fadd_rn(__fadd_rn(__fmul_rn(qx, rx), __fmul_rn(qy, ry)),
                         __fmul_rn(qz, rz));
    return __fsub_rn(__fadd_rn(sq, sr), __fadd_rn(zz, zz));
}

__global__ __launch_bounds__(256) void chamfer_direct_kernel(
    const float* __restrict__ preds, const float* __restrict__ gts,
    float* __restrict__ out)
{
    __shared__ float4 spts[256];
    int bid = blockIdx.x;
    int dir = bid / QB79;
    int qb  = bid - dir * QB79;
    int q   = qb * 256 + threadIdx.x;

    const float* qpts = (dir == 0) ? preds : gts;
    const float* rpts = (dir == 0) ? gts   : preds;

    int qc = (q < N_PTS) ? q : (N_PTS - 1);
    float qx = qpts[qc*3+0], qy = qpts[qc*3+1], qz = qpts[qc*3+2];
    float sq = np_self_dot(qx, qy, qz);
    float best = 3.4e38f;
    int   bidx = 0;

    for (int t = 0; t < N_PTS; t += 256) {
        int cnt = min(256, N_PTS - t);
        __syncthreads();
        if ((int)threadIdx.x < cnt) {
            int j = t + threadIdx.x;
            float rx = rpts[j*3+0], ry = rpts[j*3+1], rz = rpts[j*3+2];
            spts[threadIdx.x] = make_float4(rx, ry, rz, np_self_dot(rx, ry, rz));
        }
        __syncthreads();
        for (int k = 0; k < cnt; ++k) {
            float4 r = spts[k];
            float d = np_pair(sq, r.w, qx, qy, qz, r.x, r.y, r.z);
            if (d < best) { best = d; bidx = t + k; }
        }
    }
    if (q < N_PTS) {
        out[dir * N_PTS + q]       = best;
        out[(2 + dir) * N_PTS + q] = (float)bidx;
    }
}

extern "C" void kernel_launch(void* const* d_in, const int* in_sizes, int n_in,
                              void* d_out, int out_size, void* d_ws, size_t ws_size,
                              hipStream_t stream) {
    const float* preds = (const float*)d_in[0];  // [20000, 3]
    const float* gts   = (const float*)d_in[1];  // [1, 20000, 3]
    float* out = (float*)d_out;

    char* w = (char*)d_ws;
    size_t sorted_b = (size_t)2 * N_PTS * sizeof(float4);   // 640000
    size_t bstart_b = (size_t)2 * (NC + 1) * sizeof(int);   // 131080
    size_t cursor_b = (size_t)2 * NC * sizeof(int);         // 131072
    size_t need = sorted_b + bstart_b + cursor_b;

    if (ws_size >= need) {
        float4* sorted = (float4*)w;
        int* bstart = (int*)(w + sorted_b);
        int* cursor = (int*)(w + sorted_b + bstart_b);

        hipMemsetAsync(cursor, 0, cursor_b, stream);
        k_hist<<<(2 * N_PTS + 255) / 256, 256, 0, stream>>>(preds, gts, cursor);
        k_scan<<<2, 1024, 0, stream>>>(cursor, bstart);
        k_scatter<<<(2 * N_PTS + 255) / 256, 256, 0, stream>>>(
            preds, gts, cursor, sorted);
        k_main<<<2 * N_PTS, 64, 0, stream>>>(sorted, bstart, out);
    } else {
        chamfer_direct_kernel<<<2 * QB79, 256, 0, stream>>>(preds, gts, out);
    }
}